// Round 21
// baseline (139.876 us; speedup 1.0000x reference)
//
#include <hip/hip_runtime.h>
#include <math.h>

// Problem constants
#define B 16
#define H 1024
#define W 1024
#define TOPK 5000
#define SCORES_TH 0.2f

// selection pipeline constants
#define SELCAP 8192        // max selected per batch
#define NB2 9831           // buckets over value bits[31:11]
#define OFFB2 510361       // bits(0.2f) >> 11
#define GS2 9840           // padded per-batch stride for G/hist (>= NB2+2)
#define SCHUNK 10          // ceil(NB2/1024)

// wave-NMS geometry (float4 lanes — 4 cols/lane, 1 shfl/col)
#define XSTRIPS 5          // ceil(1024/252)
#define YSTRIPS 64
#define SROWS 16           // output rows per wave
#define SCOLS 252          // output cols per wave (64 lanes x 4 - 4 halo)
#define WCAP 256           // per-slot key capacity (mean 161/strip, +7 sigma)
#define SLOTS (XSTRIPS * YSTRIPS)      // 320 per batch
#define CAPB (SLOTS * WCAP)            // 81920 virtual entries per batch

// ---------------------------------------------------------------------------
// K1: wave-synchronous single 5x5 NMS (== double NMS, proven identity).
// FROZEN (round 17, ~30 us) + hist zeroing (1 store/thread, replaces memset).
// Keys: (value_bits << 32) | ~idx  (desc value, asc index) — unique per pixel.
// ---------------------------------------------------------------------------
__global__ __launch_bounds__(256) void nms_wave(
    const float* __restrict__ s,
    unsigned* __restrict__ wc,
    unsigned long long* __restrict__ cand,
    unsigned* __restrict__ hist)
{
    __shared__ unsigned long long wbuf[4][WCAP];   // 8 KB, wave-private slices
    __shared__ unsigned wcnt[4];

    const int tid  = threadIdx.x;

    // zero hist for the downstream pipeline (kernel boundary orders it)
    {
        unsigned zi = blockIdx.x * 256u + (unsigned)tid;
        if (zi < (unsigned)(B * GS2)) hist[zi] = 0u;
    }

    const int w    = tid >> 6;                     // wave within block
    const int lane = tid & 63;
    const int gw   = blockIdx.x * 4 + w;           // 0 .. 5119
    const int xs   = gw % XSTRIPS;
    const int t    = gw / XSTRIPS;                 // 0 .. 1023
    const int ys   = t & (YSTRIPS - 1);
    const int b    = t >> 6;
    const int slot = xs * YSTRIPS + ys;            // 0 .. 319

    if (lane == 0) wcnt[w] = 0;

    const float* sb = s + (size_t)b * (H * W);
    const int c0 = xs * SCOLS - 2 + 4 * lane;      // lane's first col (dword-aligned)
    const int y0 = ys * SROWS;
    const bool wfast = (xs > 0) & (xs < XSTRIPS - 1);   // wave-uniform fast path

    bool inb[4], emitok[4];
    #pragma unroll
    for (int j = 0; j < 4; ++j) {
        int col = c0 + j, idx4 = 4 * lane + j;
        inb[j]    = (col >= 0) & (col < W);
        emitok[j] = inb[j] & (idx4 >= 2) & (idx4 <= 253);
    }

    float ring[4][4], p1[4], p2[4];
    #pragma unroll
    for (int j = 0; j < 4; ++j) {
        ring[j][0] = ring[j][1] = ring[j][2] = ring[j][3] = -INFINITY;
        p1[j] = p2[j] = -INFINITY;
    }

    #pragma unroll 4
    for (int gy = y0 - 2; gy <= y0 + SROWS + 1; ++gy) {
        // ---- load row ------------------------------------------------------
        float a[4];
        const bool yin = (gy >= 0) & (gy < H);
        if (yin & wfast) {
            float4 v = *(const float4*)(sb + (size_t)gy * W + c0);
            a[0] = v.x; a[1] = v.y; a[2] = v.z; a[3] = v.w;
        } else if (yin) {
            #pragma unroll
            for (int j = 0; j < 4; ++j)
                a[j] = inb[j] ? sb[(size_t)gy * W + c0 + j] : -INFINITY;
        } else {
            #pragma unroll
            for (int j = 0; j < 4; ++j) a[j] = -INFINITY;
        }

        // ---- horizontal 5-max: 3 pair-maxes + 4 shfls for 4 cols -----------
        float pm01 = fmaxf(a[0], a[1]);
        float pm12 = fmaxf(a[1], a[2]);
        float pm23 = fmaxf(a[2], a[3]);
        float Lh  = __shfl_up(pm23, 1);            // cols c0-2,c0-1
        float La3 = __shfl_up(a[3], 1);            // col  c0-1
        float Ra0 = __shfl_down(a[0], 1);          // col  c0+4
        float Rp  = __shfl_down(pm01, 1);          // cols c0+4,c0+5
        float h[4];
        h[0] = fmaxf(fmaxf(Lh,  pm01), a[2]);      // c0-2..c0+2
        h[1] = fmaxf(fmaxf(La3, pm01), pm23);      // c0-1..c0+3
        h[2] = fmaxf(fmaxf(pm01, pm23), Ra0);      // c0  ..c0+4
        h[3] = fmaxf(fmaxf(pm12, pm23), Rp);       // c0+1..c0+5

        // ---- emit output row r = gy-2 --------------------------------------
        if (gy >= y0 + 2) {
            const int r = gy - 2;
            #pragma unroll
            for (int j = 0; j < 4; ++j) {
                float vm = fmaxf(fmaxf(fmaxf(ring[j][0], ring[j][1]),
                                       fmaxf(ring[j][2], ring[j][3])), h[j]);
                bool pk = emitok[j] & (p2[j] > SCORES_TH) & (p2[j] == vm);
                if (pk) {
                    unsigned idx = (unsigned)(r * W + c0 + j);
                    unsigned long long key =
                        ((unsigned long long)__float_as_uint(p2[j]) << 32) | (unsigned)(~idx);
                    unsigned pi = atomicAdd(&wcnt[w], 1u);   // LDS, wave-private
                    if (pi < WCAP) wbuf[w][pi] = key;
                }
            }
        }

        // ---- shift rings (renamed by unroll) --------------------------------
        #pragma unroll
        for (int j = 0; j < 4; ++j) {
            ring[j][0] = ring[j][1]; ring[j][1] = ring[j][2];
            ring[j][2] = ring[j][3]; ring[j][3] = h[j];
            p2[j] = p1[j]; p1[j] = a[j];
        }
    }

    // ---- flush to deterministic slot (no atomics, fully coalesced) ----------
    unsigned n = wcnt[w]; if (n > WCAP) n = WCAP;
    const size_t base = (size_t)b * CAPB + (size_t)slot * WCAP;
    for (unsigned k = (unsigned)lane; k < n; k += 64)
        cand[base + k] = wbuf[w][k];
    if (lane == 0) wc[b * SLOTS + slot] = n;
}

// ---------------------------------------------------------------------------
// K2a: grid-parallel histogram — one block per slot (wc is a scalar
// broadcast, key load is one coalesced transaction, 5120 blocks hide latency).
// ---------------------------------------------------------------------------
__global__ __launch_bounds__(256) void hist_build(
    const unsigned* __restrict__ wc,
    const unsigned long long* __restrict__ cand,
    unsigned* __restrict__ hist)
{
    const int slot = blockIdx.x, b = blockIdx.y;
    unsigned n = wc[b * SLOTS + slot]; if (n > WCAP) n = WCAP;
    const unsigned tid = threadIdx.x;
    if (tid < n) {
        unsigned long long key = cand[(size_t)b * CAPB + (size_t)slot * WCAP + tid];
        unsigned bits = (unsigned)(key >> 32);
        int bk = (int)(bits >> 11) - OFFB2;
        bk = bk < 0 ? 0 : (bk > NB2 - 1 ? NB2 - 1 : bk);
        atomicAdd(&hist[(size_t)b * GS2 + bk], 1u);
    }
}

// ---------------------------------------------------------------------------
// K2b: scan-only — suffix-sum the histogram (wave-shfl scan, 2 barriers),
// find threshold T, publish G, selC, Tarr. One block per batch (tiny work).
// I[bk] = #{keys in buckets >= bk}; segment of bucket bk = [I[bk+1], I[bk]).
// ---------------------------------------------------------------------------
__global__ __launch_bounds__(1024) void scanT(
    const unsigned* __restrict__ hist,
    unsigned* __restrict__ G,
    unsigned* __restrict__ selC,
    unsigned* __restrict__ Tarr)
{
    const int b = blockIdx.x;
    __shared__ unsigned I[NB2 + 2];   // 39.3 KB
    __shared__ unsigned wsum[16];
    __shared__ int Tsh;
    const int tid  = threadIdx.x;
    const int wv   = tid >> 6;
    const int lane = tid & 63;
    const unsigned* hb = hist + (size_t)b * GS2;

    #pragma unroll 10
    for (int i = tid; i < NB2 + 2; i += 1024) I[i] = (i < NB2) ? hb[i] : 0u;
    if (tid == 0) Tsh = 0;
    __syncthreads();

    // suffix-sum over descending bk; r = NB2-1-bk, chunk of SCHUNK per thread
    unsigned local = 0;
    #pragma unroll
    for (int u = 0; u < SCHUNK; ++u) {
        int r = tid * SCHUNK + u;
        if (r < NB2) local += I[NB2 - 1 - r];
    }
    unsigned incl = local;
    #pragma unroll
    for (int off = 1; off < 64; off <<= 1) {
        unsigned v = __shfl_up(incl, off);
        if (lane >= off) incl += v;
    }
    if (lane == 63) wsum[wv] = incl;
    __syncthreads();
    if (tid < 16) {
        unsigned o = wsum[tid];
        unsigned x = o;
        #pragma unroll
        for (int off = 1; off < 16; off <<= 1) {
            unsigned v = __shfl_up(x, off);
            if (tid >= off) x += v;
        }
        wsum[tid] = x - o;                 // exclusive prefix of wave totals
    }
    __syncthreads();
    unsigned run = wsum[wv] + (incl - local);   // thread's global exclusive prefix
    #pragma unroll
    for (int u = 0; u < SCHUNK; ++u) {
        int r = tid * SCHUNK + u;
        if (r < NB2) {
            int bk = NB2 - 1 - r;
            run += I[bk];
            I[bk] = run;                   // I becomes inclusive suffix sum
        }
    }
    __syncthreads();

    // T = max bk with I[bk] >= TOPK (0 if total < TOPK -> select all)
    int localT = -1;
    #pragma unroll
    for (int u = 0; u < SCHUNK; ++u) {
        int r = tid * SCHUNK + u;
        if (r < NB2) {
            int bk = NB2 - 1 - r;
            if (I[bk] >= TOPK && bk > localT) localT = bk;
        }
    }
    if (localT >= 0) atomicMax(&Tsh, localT);
    __syncthreads();
    const int T = Tsh;
    if (tid == 0) { selC[b] = I[T]; Tarr[b] = (unsigned)T; }

    unsigned* Gb = G + (size_t)b * GS2;
    #pragma unroll 10
    for (int i = tid; i < NB2 + 2; i += 1024) Gb[i] = I[i];
}

// ---------------------------------------------------------------------------
// K2c: grid-parallel bucket-grouped scatter — one block per slot, global
// cursor atomics on G[bk+1]. Post-scatter: G[bk+1] == I[bk] for all bk >= T
// (R12-proven recovery), so K3 reads segments from the mutated G.
// ---------------------------------------------------------------------------
__global__ __launch_bounds__(256) void scatter_sel(
    const unsigned* __restrict__ wc,
    const unsigned long long* __restrict__ cand,
    const unsigned* __restrict__ Tarr,
    unsigned* __restrict__ G,
    unsigned long long* __restrict__ sel)
{
    const int slot = blockIdx.x, b = blockIdx.y;
    unsigned n = wc[b * SLOTS + slot]; if (n > WCAP) n = WCAP;
    const unsigned tid = threadIdx.x;
    if (tid < n) {
        unsigned long long key = cand[(size_t)b * CAPB + (size_t)slot * WCAP + tid];
        unsigned bits = (unsigned)(key >> 32);
        int bk = (int)(bits >> 11) - OFFB2;
        bk = bk < 0 ? 0 : (bk > NB2 - 1 ? NB2 - 1 : bk);
        if (bk >= (int)Tarr[b]) {
            unsigned p = atomicAdd(&G[(size_t)b * GS2 + bk + 1], 1u);
            if (p < SELCAP) sel[(size_t)b * SELCAP + p] = key;
        }
    }
}

// ---------------------------------------------------------------------------
// K3: two-level exact rank, 4 lanes/key + zero-fill of ranks [C, TOPK).
// Post-scatter G recovery: start = G[bk+2] (== I[bk+1]), end = G[bk+1]
// (== I[bk]). Otherwise frozen (round 13).
// ---------------------------------------------------------------------------
__global__ __launch_bounds__(256) void rank_refine(
    const float* __restrict__ s,
    const unsigned long long* __restrict__ sel,
    const unsigned* __restrict__ selC,
    const unsigned* __restrict__ G,
    float* __restrict__ out)
{
    const int b = blockIdx.y;
    unsigned C = selC[b]; if (C > SELCAP) C = SELCAP;
    const int tid = threadIdx.x;
    const unsigned g = blockIdx.x * 64u + (unsigned)(tid >> 2);
    const int l = tid & 3;

    if (g >= C) {                     // zero-fill unclaimed output ranks
        if (g < TOPK && l == 0) {
            out[((size_t)b * TOPK + g) * 2 + 0] = 0.0f;
            out[((size_t)b * TOPK + g) * 2 + 1] = 0.0f;
            out[(size_t)B * TOPK * 2 + (size_t)b * TOPK + g] = 0.0f;
        }
        return;
    }

    const unsigned long long* sb = sel + (size_t)b * SELCAP;
    const unsigned long long my = sb[g];
    unsigned bits = (unsigned)(my >> 32);
    int bk = (int)(bits >> 11) - OFFB2;
    bk = bk < 0 ? 0 : (bk > NB2 - 1 ? NB2 - 1 : bk);

    const unsigned* Gb = G + (size_t)b * GS2;
    unsigned start = Gb[bk + 2], end = Gb[bk + 1];  // post-scatter recovery
    if (end > SELCAP) end = SELCAP;
    unsigned rank = 0;
    for (unsigned j = start + (unsigned)l; j < end; j += 4)
        rank += (sb[j] > my) ? 1u : 0u;

    float v = __uint_as_float(bits);
    unsigned idx = ~((unsigned)my);
    int y = (int)(idx >> 10), x = (int)(idx & 1023);
    const float* smb = s + (size_t)b * (H * W);
    float wsum = 0.f, ox = 0.f, oy = 0.f;
    for (int c = l; c < 25; c += 4) {
        int dy = c / 5 - 2, dx = c - (c / 5) * 5 - 2;
        int yy = y + dy, xx = x + dx;
        bool inb = (yy >= 0 && yy < H && xx >= 0 && xx < W);
        int yc = min(max(yy, 0), H - 1), xc = min(max(xx, 0), W - 1);
        float p = smb[yc * W + xc];
        float lg = inb ? p * 10.0f : -1e9f;   // 1/TEMPERATURE = 10
        float e = expf(lg);
        wsum += e; ox += e * (float)dx; oy += e * (float)dy;
    }
    rank += __shfl_xor(rank, 1); rank += __shfl_xor(rank, 2);
    wsum += __shfl_xor(wsum, 1); wsum += __shfl_xor(wsum, 2);
    ox   += __shfl_xor(ox, 1);   ox   += __shfl_xor(ox, 2);
    oy   += __shfl_xor(oy, 1);   oy   += __shfl_xor(oy, 2);

    unsigned frank = start + rank;
    if (l == 0 && frank < TOPK) {
        float offx = ox / wsum, offy = oy / wsum;
        out[((size_t)b * TOPK + frank) * 2 + 0] = (float)x + offx;
        out[((size_t)b * TOPK + frank) * 2 + 1] = (float)y + offy;
        out[(size_t)B * TOPK * 2 + (size_t)b * TOPK + frank] = v;
    }
}

// ---------------------------------------------------------------------------
extern "C" void kernel_launch(void* const* d_in, const int* in_sizes, int n_in,
                              void* d_out, int out_size, void* d_ws, size_t ws_size,
                              hipStream_t stream)
{
    const float* s = (const float*)d_in[0];
    float* out = (float*)d_out;
    char* ws = (char*)d_ws;

    size_t off = 0;
    unsigned* wc            = (unsigned*)(ws + off);  off += (size_t)B * SLOTS * 4;  // 20 KB
    unsigned* selC          = (unsigned*)(ws + off);  off += 64;
    unsigned* Tarr          = (unsigned*)(ws + off);  off += 64;
    unsigned* G             = (unsigned*)(ws + off);  off += (size_t)B * GS2 * 4;    // 630 KB
    unsigned* hist          = (unsigned*)(ws + off);  off += (size_t)B * GS2 * 4;    // 630 KB
    unsigned long long* sel = (unsigned long long*)(ws + off); off += (size_t)B * SELCAP * 8; // 1 MB
    unsigned long long* cand= (unsigned long long*)(ws + off);                       // 10.5 MB

    nms_wave<<<dim3(XSTRIPS * YSTRIPS * B / 4), dim3(256), 0, stream>>>(s, wc, cand, hist);
    hist_build<<<dim3(SLOTS, B), dim3(256), 0, stream>>>(wc, cand, hist);
    scanT<<<dim3(B), dim3(1024), 0, stream>>>(hist, G, selC, Tarr);
    scatter_sel<<<dim3(SLOTS, B), dim3(256), 0, stream>>>(wc, cand, Tarr, G, sel);
    rank_refine<<<dim3(SELCAP * 4 / 256, B), dim3(256), 0, stream>>>(s, sel, selC, G, out);
}

// Round 22
// 99.210 us; speedup vs baseline: 1.4099x; 1.4099x over previous
//
#include <hip/hip_runtime.h>
#include <math.h>

// Problem constants
#define B 16
#define H 1024
#define W 1024
#define TOPK 5000
#define SCORES_TH 0.2f

// selection pipeline constants
#define SELCAP 8192        // max selected per batch
#define NB2 9831           // buckets over value bits[31:11]
#define OFFB2 510361       // bits(0.2f) >> 11
#define GS2 9840           // padded per-batch stride for G / partials
#define SCHUNK 10          // ceil(NB2/1024)

// wave-NMS geometry (float4 lanes — 4 cols/lane, 1 shfl/col)
#define XSTRIPS 5          // ceil(1024/252)
#define YSTRIPS 64
#define SROWS 16           // output rows per wave
#define SCOLS 252          // output cols per wave (64 lanes x 4 - 4 halo)
#define WCAP 256           // per-slot key capacity (mean 161/strip, +7 sigma)
#define SLOTS (XSTRIPS * YSTRIPS)      // 320 per batch
#define CAPB (SLOTS * WCAP)            // 81920 virtual entries per batch
#define NPB 16             // histogram partials per batch
#define SPP 20             // slots per partial (SLOTS/NPB)

// ---------------------------------------------------------------------------
// K1: wave-synchronous single 5x5 NMS (== double NMS, proven identity).
// FROZEN (round 17, ~30 us). Deterministic per-wave slots; no atomics,
// no counters, no memsets anywhere in the pipeline.
// Keys: (value_bits << 32) | ~idx  (desc value, asc index) — unique per pixel.
// ---------------------------------------------------------------------------
__global__ __launch_bounds__(256) void nms_wave(
    const float* __restrict__ s,
    unsigned* __restrict__ wc,
    unsigned long long* __restrict__ cand)
{
    __shared__ unsigned long long wbuf[4][WCAP];   // 8 KB, wave-private slices
    __shared__ unsigned wcnt[4];

    const int tid  = threadIdx.x;
    const int w    = tid >> 6;                     // wave within block
    const int lane = tid & 63;
    const int gw   = blockIdx.x * 4 + w;           // 0 .. 5119
    const int xs   = gw % XSTRIPS;
    const int t    = gw / XSTRIPS;                 // 0 .. 1023
    const int ys   = t & (YSTRIPS - 1);
    const int b    = t >> 6;
    const int slot = xs * YSTRIPS + ys;            // 0 .. 319

    if (lane == 0) wcnt[w] = 0;

    const float* sb = s + (size_t)b * (H * W);
    const int c0 = xs * SCOLS - 2 + 4 * lane;      // lane's first col (dword-aligned)
    const int y0 = ys * SROWS;
    const bool wfast = (xs > 0) & (xs < XSTRIPS - 1);   // wave-uniform fast path

    bool inb[4], emitok[4];
    #pragma unroll
    for (int j = 0; j < 4; ++j) {
        int col = c0 + j, idx4 = 4 * lane + j;
        inb[j]    = (col >= 0) & (col < W);
        emitok[j] = inb[j] & (idx4 >= 2) & (idx4 <= 253);
    }

    float ring[4][4], p1[4], p2[4];
    #pragma unroll
    for (int j = 0; j < 4; ++j) {
        ring[j][0] = ring[j][1] = ring[j][2] = ring[j][3] = -INFINITY;
        p1[j] = p2[j] = -INFINITY;
    }

    #pragma unroll 4
    for (int gy = y0 - 2; gy <= y0 + SROWS + 1; ++gy) {
        // ---- load row ------------------------------------------------------
        float a[4];
        const bool yin = (gy >= 0) & (gy < H);
        if (yin & wfast) {
            float4 v = *(const float4*)(sb + (size_t)gy * W + c0);
            a[0] = v.x; a[1] = v.y; a[2] = v.z; a[3] = v.w;
        } else if (yin) {
            #pragma unroll
            for (int j = 0; j < 4; ++j)
                a[j] = inb[j] ? sb[(size_t)gy * W + c0 + j] : -INFINITY;
        } else {
            #pragma unroll
            for (int j = 0; j < 4; ++j) a[j] = -INFINITY;
        }

        // ---- horizontal 5-max: 3 pair-maxes + 4 shfls for 4 cols -----------
        float pm01 = fmaxf(a[0], a[1]);
        float pm12 = fmaxf(a[1], a[2]);
        float pm23 = fmaxf(a[2], a[3]);
        float Lh  = __shfl_up(pm23, 1);            // cols c0-2,c0-1
        float La3 = __shfl_up(a[3], 1);            // col  c0-1
        float Ra0 = __shfl_down(a[0], 1);          // col  c0+4
        float Rp  = __shfl_down(pm01, 1);          // cols c0+4,c0+5
        float h[4];
        h[0] = fmaxf(fmaxf(Lh,  pm01), a[2]);      // c0-2..c0+2
        h[1] = fmaxf(fmaxf(La3, pm01), pm23);      // c0-1..c0+3
        h[2] = fmaxf(fmaxf(pm01, pm23), Ra0);      // c0  ..c0+4
        h[3] = fmaxf(fmaxf(pm12, pm23), Rp);       // c0+1..c0+5

        // ---- emit output row r = gy-2 --------------------------------------
        if (gy >= y0 + 2) {
            const int r = gy - 2;
            #pragma unroll
            for (int j = 0; j < 4; ++j) {
                float vm = fmaxf(fmaxf(fmaxf(ring[j][0], ring[j][1]),
                                       fmaxf(ring[j][2], ring[j][3])), h[j]);
                bool pk = emitok[j] & (p2[j] > SCORES_TH) & (p2[j] == vm);
                if (pk) {
                    unsigned idx = (unsigned)(r * W + c0 + j);
                    unsigned long long key =
                        ((unsigned long long)__float_as_uint(p2[j]) << 32) | (unsigned)(~idx);
                    unsigned pi = atomicAdd(&wcnt[w], 1u);   // LDS, wave-private
                    if (pi < WCAP) wbuf[w][pi] = key;
                }
            }
        }

        // ---- shift rings (renamed by unroll) --------------------------------
        #pragma unroll
        for (int j = 0; j < 4; ++j) {
            ring[j][0] = ring[j][1]; ring[j][1] = ring[j][2];
            ring[j][2] = ring[j][3]; ring[j][3] = h[j];
            p2[j] = p1[j]; p1[j] = a[j];
        }
    }

    // ---- flush to deterministic slot (no atomics, fully coalesced) ----------
    unsigned n = wcnt[w]; if (n > WCAP) n = WCAP;
    const size_t base = (size_t)b * CAPB + (size_t)slot * WCAP;
    for (unsigned k = (unsigned)lane; k < n; k += 64)
        cand[base + k] = wbuf[w][k];
    if (lane == 0) wc[b * SLOTS + slot] = n;
}

// ---------------------------------------------------------------------------
// K2a: privatized histogram — block (p,b) LDS-histograms slots
// [p*SPP, (p+1)*SPP) and STORES its partial (no global atomics, no zeroing).
// 256 blocks x 1024 threads; 5 unrolled loads/thread pipeline.
// ---------------------------------------------------------------------------
__global__ __launch_bounds__(1024) void hist_part_build(
    const unsigned* __restrict__ wc,
    const unsigned long long* __restrict__ cand,
    unsigned* __restrict__ hist_part)
{
    const int p = blockIdx.x, b = blockIdx.y;
    __shared__ unsigned lhist[NB2];   // 39.3 KB
    __shared__ unsigned lwc[SPP];
    const int tid = threadIdx.x;

    for (int i = tid; i < NB2; i += 1024) lhist[i] = 0;
    if (tid < SPP) {
        unsigned n = wc[b * SLOTS + p * SPP + tid];
        lwc[tid] = n > WCAP ? WCAP : n;
    }
    __syncthreads();

    const unsigned long long* cb =
        cand + (size_t)b * CAPB + (size_t)p * SPP * WCAP;
    #pragma unroll 5
    for (int k = tid; k < SPP * WCAP; k += 1024) {
        unsigned long long key = cb[k];            // unconditional — pipelines
        unsigned bits = (unsigned)(key >> 32);
        int bk = (int)(bits >> 11) - OFFB2;
        bk = bk < 0 ? 0 : (bk > NB2 - 1 ? NB2 - 1 : bk);
        if ((k & (WCAP - 1)) < lwc[k >> 8])
            atomicAdd(&lhist[bk], 1u);             // LDS atomic
    }
    __syncthreads();

    unsigned* hp = hist_part + ((size_t)b * NPB + p) * GS2;
    for (int i = tid; i < NB2; i += 1024) hp[i] = lhist[i];
}

// ---------------------------------------------------------------------------
// K2b: scan-only — merge 16 partials (unrolled independent loads), wave-shfl
// suffix scan, threshold T, publish G/selC/Tarr. One block per batch.
// I[bk] = #{keys in buckets >= bk}; segment of bucket bk = [I[bk+1], I[bk]).
// ---------------------------------------------------------------------------
__global__ __launch_bounds__(1024) void scanT(
    const unsigned* __restrict__ hist_part,
    unsigned* __restrict__ G,
    unsigned* __restrict__ selC,
    unsigned* __restrict__ Tarr)
{
    const int b = blockIdx.x;
    __shared__ unsigned I[NB2 + 2];   // 39.3 KB
    __shared__ unsigned wsum[16];
    __shared__ int Tsh;
    const int tid  = threadIdx.x;
    const int wv   = tid >> 6;
    const int lane = tid & 63;
    const unsigned* hp = hist_part + (size_t)b * NPB * GS2;

    for (int i = tid; i < NB2 + 2; i += 1024) {
        unsigned sum = 0;
        if (i < NB2) {
            #pragma unroll
            for (int p = 0; p < NPB; ++p)
                sum += hp[(size_t)p * GS2 + i];    // 16 independent loads
        }
        I[i] = sum;
    }
    if (tid == 0) Tsh = 0;
    __syncthreads();

    // suffix-sum over descending bk; r = NB2-1-bk, chunk of SCHUNK per thread
    unsigned local = 0;
    #pragma unroll
    for (int u = 0; u < SCHUNK; ++u) {
        int r = tid * SCHUNK + u;
        if (r < NB2) local += I[NB2 - 1 - r];
    }
    unsigned incl = local;
    #pragma unroll
    for (int off = 1; off < 64; off <<= 1) {
        unsigned v = __shfl_up(incl, off);
        if (lane >= off) incl += v;
    }
    if (lane == 63) wsum[wv] = incl;
    __syncthreads();
    if (tid < 16) {
        unsigned o = wsum[tid];
        unsigned x = o;
        #pragma unroll
        for (int off = 1; off < 16; off <<= 1) {
            unsigned v = __shfl_up(x, off);
            if (tid >= off) x += v;
        }
        wsum[tid] = x - o;                 // exclusive prefix of wave totals
    }
    __syncthreads();
    unsigned run = wsum[wv] + (incl - local);   // thread's global exclusive prefix
    #pragma unroll
    for (int u = 0; u < SCHUNK; ++u) {
        int r = tid * SCHUNK + u;
        if (r < NB2) {
            int bk = NB2 - 1 - r;
            run += I[bk];
            I[bk] = run;                   // I becomes inclusive suffix sum
        }
    }
    __syncthreads();

    // T = max bk with I[bk] >= TOPK (0 if total < TOPK -> select all)
    int localT = -1;
    #pragma unroll
    for (int u = 0; u < SCHUNK; ++u) {
        int r = tid * SCHUNK + u;
        if (r < NB2) {
            int bk = NB2 - 1 - r;
            if (I[bk] >= TOPK && bk > localT) localT = bk;
        }
    }
    if (localT >= 0) atomicMax(&Tsh, localT);
    __syncthreads();
    const int T = Tsh;
    if (tid == 0) { selC[b] = I[T]; Tarr[b] = (unsigned)T; }

    unsigned* Gb = G + (size_t)b * GS2;
    for (int i = tid; i < NB2 + 2; i += 1024) Gb[i] = I[i];
}

// ---------------------------------------------------------------------------
// K2c: grid-parallel bucket-grouped scatter — one block per slot; only keys
// with bk >= T (~5.2k/batch) do a global cursor atomic on G[bk+1].
// Post-scatter: G[bk+1] == I[bk] for all bk >= T (R12/R21-proven recovery).
// ---------------------------------------------------------------------------
__global__ __launch_bounds__(256) void scatter_sel(
    const unsigned* __restrict__ wc,
    const unsigned long long* __restrict__ cand,
    const unsigned* __restrict__ Tarr,
    unsigned* __restrict__ G,
    unsigned long long* __restrict__ sel)
{
    const int slot = blockIdx.x, b = blockIdx.y;
    unsigned n = wc[b * SLOTS + slot]; if (n > WCAP) n = WCAP;
    const unsigned tid = threadIdx.x;
    if (tid < n) {
        unsigned long long key = cand[(size_t)b * CAPB + (size_t)slot * WCAP + tid];
        unsigned bits = (unsigned)(key >> 32);
        int bk = (int)(bits >> 11) - OFFB2;
        bk = bk < 0 ? 0 : (bk > NB2 - 1 ? NB2 - 1 : bk);
        if (bk >= (int)Tarr[b]) {
            unsigned p = atomicAdd(&G[(size_t)b * GS2 + bk + 1], 1u);
            if (p < SELCAP) sel[(size_t)b * SELCAP + p] = key;
        }
    }
}

// ---------------------------------------------------------------------------
// K3: two-level exact rank, 4 lanes/key + zero-fill of ranks [C, TOPK).
// Post-scatter G recovery: start = G[bk+2] (== I[bk+1]), end = G[bk+1]
// (== I[bk]). FROZEN (rounds 13/21).
// ---------------------------------------------------------------------------
__global__ __launch_bounds__(256) void rank_refine(
    const float* __restrict__ s,
    const unsigned long long* __restrict__ sel,
    const unsigned* __restrict__ selC,
    const unsigned* __restrict__ G,
    float* __restrict__ out)
{
    const int b = blockIdx.y;
    unsigned C = selC[b]; if (C > SELCAP) C = SELCAP;
    const int tid = threadIdx.x;
    const unsigned g = blockIdx.x * 64u + (unsigned)(tid >> 2);
    const int l = tid & 3;

    if (g >= C) {                     // zero-fill unclaimed output ranks
        if (g < TOPK && l == 0) {
            out[((size_t)b * TOPK + g) * 2 + 0] = 0.0f;
            out[((size_t)b * TOPK + g) * 2 + 1] = 0.0f;
            out[(size_t)B * TOPK * 2 + (size_t)b * TOPK + g] = 0.0f;
        }
        return;
    }

    const unsigned long long* sb = sel + (size_t)b * SELCAP;
    const unsigned long long my = sb[g];
    unsigned bits = (unsigned)(my >> 32);
    int bk = (int)(bits >> 11) - OFFB2;
    bk = bk < 0 ? 0 : (bk > NB2 - 1 ? NB2 - 1 : bk);

    const unsigned* Gb = G + (size_t)b * GS2;
    unsigned start = Gb[bk + 2], end = Gb[bk + 1];  // post-scatter recovery
    if (end > SELCAP) end = SELCAP;
    unsigned rank = 0;
    for (unsigned j = start + (unsigned)l; j < end; j += 4)
        rank += (sb[j] > my) ? 1u : 0u;

    float v = __uint_as_float(bits);
    unsigned idx = ~((unsigned)my);
    int y = (int)(idx >> 10), x = (int)(idx & 1023);
    const float* smb = s + (size_t)b * (H * W);
    float wsum = 0.f, ox = 0.f, oy = 0.f;
    for (int c = l; c < 25; c += 4) {
        int dy = c / 5 - 2, dx = c - (c / 5) * 5 - 2;
        int yy = y + dy, xx = x + dx;
        bool inb = (yy >= 0 && yy < H && xx >= 0 && xx < W);
        int yc = min(max(yy, 0), H - 1), xc = min(max(xx, 0), W - 1);
        float p = smb[yc * W + xc];
        float lg = inb ? p * 10.0f : -1e9f;   // 1/TEMPERATURE = 10
        float e = expf(lg);
        wsum += e; ox += e * (float)dx; oy += e * (float)dy;
    }
    rank += __shfl_xor(rank, 1); rank += __shfl_xor(rank, 2);
    wsum += __shfl_xor(wsum, 1); wsum += __shfl_xor(wsum, 2);
    ox   += __shfl_xor(ox, 1);   ox   += __shfl_xor(ox, 2);
    oy   += __shfl_xor(oy, 1);   oy   += __shfl_xor(oy, 2);

    unsigned frank = start + rank;
    if (l == 0 && frank < TOPK) {
        float offx = ox / wsum, offy = oy / wsum;
        out[((size_t)b * TOPK + frank) * 2 + 0] = (float)x + offx;
        out[((size_t)b * TOPK + frank) * 2 + 1] = (float)y + offy;
        out[(size_t)B * TOPK * 2 + (size_t)b * TOPK + frank] = v;
    }
}

// ---------------------------------------------------------------------------
extern "C" void kernel_launch(void* const* d_in, const int* in_sizes, int n_in,
                              void* d_out, int out_size, void* d_ws, size_t ws_size,
                              hipStream_t stream)
{
    const float* s = (const float*)d_in[0];
    float* out = (float*)d_out;
    char* ws = (char*)d_ws;

    size_t off = 0;
    unsigned* wc            = (unsigned*)(ws + off);  off += (size_t)B * SLOTS * 4;       // 20 KB
    unsigned* selC          = (unsigned*)(ws + off);  off += 64;
    unsigned* Tarr          = (unsigned*)(ws + off);  off += 64;
    unsigned* G             = (unsigned*)(ws + off);  off += (size_t)B * GS2 * 4;         // 630 KB
    unsigned* hist_part     = (unsigned*)(ws + off);  off += (size_t)B * NPB * GS2 * 4;   // 10 MB
    unsigned long long* sel = (unsigned long long*)(ws + off); off += (size_t)B * SELCAP * 8; // 1 MB
    unsigned long long* cand= (unsigned long long*)(ws + off);                            // 10.5 MB

    nms_wave<<<dim3(XSTRIPS * YSTRIPS * B / 4), dim3(256), 0, stream>>>(s, wc, cand);
    hist_part_build<<<dim3(NPB, B), dim3(1024), 0, stream>>>(wc, cand, hist_part);
    scanT<<<dim3(B), dim3(1024), 0, stream>>>(hist_part, G, selC, Tarr);
    scatter_sel<<<dim3(SLOTS, B), dim3(256), 0, stream>>>(wc, cand, Tarr, G, sel);
    rank_refine<<<dim3(SELCAP * 4 / 256, B), dim3(256), 0, stream>>>(s, sel, selC, G, out);
}

// Round 23
// 86.403 us; speedup vs baseline: 1.6189x; 1.1482x over previous
//
#include <hip/hip_runtime.h>
#include <math.h>

// Problem constants
#define B 16
#define H 1024
#define W 1024
#define TOPK 5000
#define SCORES_TH 0.2f

// selection pipeline constants
#define CAP 65536          // compact candidate cap per batch (expected ~42k)
#define SELCAP 8192        // max selected per batch
#define NB2 9831           // buckets over value bits[31:11]
#define OFFB2 510361       // bits(0.2f) >> 11
#define GS2 9840           // padded per-batch stride for G (>= NB2+1)
#define SCHUNK 10          // ceil(NB2/1024)
#define CSTRIDE 32         // counts padded 128 B apart

// wave-NMS geometry (float4 lanes — 4 cols/lane, 1 shfl/col)
#define XSTRIPS 5          // ceil(1024/252)
#define YSTRIPS 64
#define SROWS 16           // output rows per wave
#define SCOLS 252          // output cols per wave (64 lanes x 4 - 4 halo)
#define WCAP 224           // per-wave LDS key buffer (mean ~158/strip, +5 sigma)

// ---------------------------------------------------------------------------
// K1: wave-synchronous single 5x5 NMS (== double NMS, proven identity).
// R23: ballot-compaction emit — NO LDS atomics in the hot loop (R16 had a
// serialized same-address LDS atomicAdd across ~10 lanes every row).
// mask = __ballot(pk); lane offset = popcount(mask & lanemask_lt);
// wave-uniform running base in a register. One global atomic per wave.
// Keys: (value_bits << 32) | ~idx  (desc value, asc index) — unique per pixel.
// ---------------------------------------------------------------------------
__global__ __launch_bounds__(256) void nms_wave(
    const float* __restrict__ s,
    unsigned* __restrict__ counts,
    unsigned long long* __restrict__ cand)
{
    __shared__ unsigned long long wbuf[4][WCAP];   // 7 KB, wave-private slices
    const int tid  = threadIdx.x;
    const int w    = tid >> 6;                     // wave within block
    const int lane = tid & 63;
    const int gw   = blockIdx.x * 4 + w;           // 0 .. 5119
    const int xs   = gw % XSTRIPS;
    const int t    = gw / XSTRIPS;                 // 0 .. 1023
    const int ys   = t & (YSTRIPS - 1);
    const int b    = t >> 6;

    const float* sb = s + (size_t)b * (H * W);
    const int c0 = xs * SCOLS - 2 + 4 * lane;      // lane's first col (dword-aligned)
    const int y0 = ys * SROWS;
    const bool wfast = (xs > 0) & (xs < XSTRIPS - 1);   // wave-uniform fast path
    const unsigned long long lmlt = (lane == 63) ? ~0ull >> 1
                                                 : (1ull << lane) - 1ull; // mask of lanes < me

    bool inb[4], emitok[4];
    #pragma unroll
    for (int j = 0; j < 4; ++j) {
        int col = c0 + j, idx4 = 4 * lane + j;
        inb[j]    = (col >= 0) & (col < W);
        emitok[j] = inb[j] & (idx4 >= 2) & (idx4 <= 253);
    }

    float ring[4][4], p1[4], p2[4];
    #pragma unroll
    for (int j = 0; j < 4; ++j) {
        ring[j][0] = ring[j][1] = ring[j][2] = ring[j][3] = -INFINITY;
        p1[j] = p2[j] = -INFINITY;
    }

    unsigned wbase = 0;                            // wave-uniform running count

    #pragma unroll 4
    for (int gy = y0 - 2; gy <= y0 + SROWS + 1; ++gy) {
        // ---- load row ------------------------------------------------------
        float a[4];
        const bool yin = (gy >= 0) & (gy < H);
        if (yin & wfast) {
            float4 v = *(const float4*)(sb + (size_t)gy * W + c0);
            a[0] = v.x; a[1] = v.y; a[2] = v.z; a[3] = v.w;
        } else if (yin) {
            #pragma unroll
            for (int j = 0; j < 4; ++j)
                a[j] = inb[j] ? sb[(size_t)gy * W + c0 + j] : -INFINITY;
        } else {
            #pragma unroll
            for (int j = 0; j < 4; ++j) a[j] = -INFINITY;
        }

        // ---- horizontal 5-max: 3 pair-maxes + 4 shfls for 4 cols -----------
        float pm01 = fmaxf(a[0], a[1]);
        float pm12 = fmaxf(a[1], a[2]);
        float pm23 = fmaxf(a[2], a[3]);
        float Lh  = __shfl_up(pm23, 1);            // cols c0-2,c0-1
        float La3 = __shfl_up(a[3], 1);            // col  c0-1
        float Ra0 = __shfl_down(a[0], 1);          // col  c0+4
        float Rp  = __shfl_down(pm01, 1);          // cols c0+4,c0+5
        float h[4];
        h[0] = fmaxf(fmaxf(Lh,  pm01), a[2]);      // c0-2..c0+2
        h[1] = fmaxf(fmaxf(La3, pm01), pm23);      // c0-1..c0+3
        h[2] = fmaxf(fmaxf(pm01, pm23), Ra0);      // c0  ..c0+4
        h[3] = fmaxf(fmaxf(pm12, pm23), Rp);       // c0+1..c0+5

        // ---- emit output row r = gy-2 via ballot compaction -----------------
        if (gy >= y0 + 2) {
            const int r = gy - 2;
            #pragma unroll
            for (int j = 0; j < 4; ++j) {
                float vm = fmaxf(fmaxf(fmaxf(ring[j][0], ring[j][1]),
                                       fmaxf(ring[j][2], ring[j][3])), h[j]);
                bool pk = emitok[j] & (p2[j] > SCORES_TH) & (p2[j] == vm);
                unsigned long long mask = __ballot(pk);
                if (pk) {
                    unsigned pi = wbase + (unsigned)__popcll(mask & lmlt);
                    unsigned idx = (unsigned)(r * W + c0 + j);
                    unsigned long long key =
                        ((unsigned long long)__float_as_uint(p2[j]) << 32) | (unsigned)(~idx);
                    if (pi < WCAP) wbuf[w][pi] = key;
                    else {                          // overflow: direct reserved write
                        unsigned gp = atomicAdd(&counts[b * CSTRIDE], 1u);
                        if (gp < CAP) cand[(size_t)b * CAP + gp] = key;
                    }
                }
                wbase += (unsigned)__popcll(mask); // wave-uniform
            }
        }

        // ---- shift rings (renamed by unroll) --------------------------------
        #pragma unroll
        for (int j = 0; j < 4; ++j) {
            ring[j][0] = ring[j][1]; ring[j][1] = ring[j][2];
            ring[j][2] = ring[j][3]; ring[j][3] = h[j];
            p2[j] = p1[j]; p1[j] = a[j];
        }
    }

    // ---- flush: one global atomic per wave, coalesced copy ------------------
    unsigned n = wbase; if (n > WCAP) n = WCAP;
    unsigned base = 0;
    if (lane == 0) base = atomicAdd(&counts[b * CSTRIDE], n);
    base = __shfl(base, 0);
    for (unsigned k = (unsigned)lane; k < n; k += 64)
        if (base + k < CAP) cand[(size_t)b * CAP + base + k] = wbuf[w][k];
}

// ---------------------------------------------------------------------------
// K2: fused LDS-histogram + wave-shfl suffix-sum scan + threshold + publish G
// + scatter (LDS cursors). One block/batch, COMPACT cand iteration (R16's
// proven ~17 us form; R17's wave-shfl scan kept — its regression was the
// slot-chunking, not the scan).
// I[bk] = #{keys in buckets >= bk}; segment of bucket bk = [I[bk+1], I[bk]).
// ---------------------------------------------------------------------------
__global__ __launch_bounds__(1024) void scan_scatter(
    const unsigned* __restrict__ counts,
    const unsigned long long* __restrict__ cand,
    unsigned* __restrict__ G,
    unsigned* __restrict__ selC,
    unsigned long long* __restrict__ sel)
{
    const int b = blockIdx.x;
    __shared__ unsigned I[NB2 + 1];   // 39.3 KB
    __shared__ unsigned wsum[16];
    __shared__ int Tsh;
    const int tid  = threadIdx.x;
    const int wv   = tid >> 6;
    const int lane = tid & 63;

    for (int i = tid; i < NB2 + 1; i += 1024) I[i] = 0;
    if (tid == 0) Tsh = 0;
    __syncthreads();

    unsigned M = counts[b * CSTRIDE]; if (M > CAP) M = CAP;
    const unsigned long long* cb = cand + (size_t)b * CAP;

    // ---- histogram over compact keys --------------------------------------
    for (unsigned i = (unsigned)tid; i < M; i += 1024) {
        unsigned bits = (unsigned)(cb[i] >> 32);
        int bk = (int)(bits >> 11) - OFFB2;
        bk = bk < 0 ? 0 : (bk > NB2 - 1 ? NB2 - 1 : bk);
        atomicAdd(&I[bk], 1u);
    }
    __syncthreads();

    // ---- suffix-sum via wave-shfl scan (2 barriers) -----------------------
    unsigned local = 0;
    #pragma unroll
    for (int u = 0; u < SCHUNK; ++u) {
        int r = tid * SCHUNK + u;
        if (r < NB2) local += I[NB2 - 1 - r];
    }
    unsigned incl = local;
    #pragma unroll
    for (int off = 1; off < 64; off <<= 1) {
        unsigned v = __shfl_up(incl, off);
        if (lane >= off) incl += v;
    }
    if (lane == 63) wsum[wv] = incl;
    __syncthreads();
    if (tid < 16) {
        unsigned o = wsum[tid];
        unsigned x = o;
        #pragma unroll
        for (int off = 1; off < 16; off <<= 1) {
            unsigned v = __shfl_up(x, off);
            if (tid >= off) x += v;
        }
        wsum[tid] = x - o;                 // exclusive prefix of wave totals
    }
    __syncthreads();
    unsigned run = wsum[wv] + (incl - local);   // thread's global exclusive prefix
    #pragma unroll
    for (int u = 0; u < SCHUNK; ++u) {
        int r = tid * SCHUNK + u;
        if (r < NB2) {
            int bk = NB2 - 1 - r;
            run += I[bk];
            I[bk] = run;                   // I becomes inclusive suffix sum
        }
    }
    __syncthreads();

    // ---- T = max bk with I[bk] >= TOPK (0 if total < TOPK) ----------------
    int localT = -1;
    #pragma unroll
    for (int u = 0; u < SCHUNK; ++u) {
        int r = tid * SCHUNK + u;
        if (r < NB2) {
            int bk = NB2 - 1 - r;
            if (I[bk] >= TOPK && bk > localT) localT = bk;
        }
    }
    if (localT >= 0) atomicMax(&Tsh, localT);
    __syncthreads();
    const int T = Tsh;
    if (tid == 0) selC[b] = I[T];

    // ---- publish clean segment table G, then scatter with LDS cursors -----
    unsigned* Gb = G + (size_t)b * GS2;
    for (int i = tid; i < NB2 + 1; i += 1024) Gb[i] = I[i];
    __syncthreads();

    for (unsigned i = (unsigned)tid; i < M; i += 1024) {
        unsigned long long key = cb[i];
        unsigned bits = (unsigned)(key >> 32);
        int bk = (int)(bits >> 11) - OFFB2;
        bk = bk < 0 ? 0 : (bk > NB2 - 1 ? NB2 - 1 : bk);
        if (bk >= T) {
            unsigned p = atomicAdd(&I[bk + 1], 1u);   // LDS cursor
            if (p < SELCAP) sel[(size_t)b * SELCAP + p] = key;
        }
    }
}

// ---------------------------------------------------------------------------
// K3: two-level exact rank, 4 lanes/key + zero-fill of ranks [C, TOPK).
// FROZEN (round 13/16).
// ---------------------------------------------------------------------------
__global__ __launch_bounds__(256) void rank_refine(
    const float* __restrict__ s,
    const unsigned long long* __restrict__ sel,
    const unsigned* __restrict__ selC,
    const unsigned* __restrict__ G,
    float* __restrict__ out)
{
    const int b = blockIdx.y;
    unsigned C = selC[b]; if (C > SELCAP) C = SELCAP;
    const int tid = threadIdx.x;
    const unsigned g = blockIdx.x * 64u + (unsigned)(tid >> 2);
    const int l = tid & 3;

    if (g >= C) {                     // zero-fill unclaimed output ranks
        if (g < TOPK && l == 0) {
            out[((size_t)b * TOPK + g) * 2 + 0] = 0.0f;
            out[((size_t)b * TOPK + g) * 2 + 1] = 0.0f;
            out[(size_t)B * TOPK * 2 + (size_t)b * TOPK + g] = 0.0f;
        }
        return;
    }

    const unsigned long long* sb = sel + (size_t)b * SELCAP;
    const unsigned long long my = sb[g];
    unsigned bits = (unsigned)(my >> 32);
    int bk = (int)(bits >> 11) - OFFB2;
    bk = bk < 0 ? 0 : (bk > NB2 - 1 ? NB2 - 1 : bk);

    const unsigned* Gb = G + (size_t)b * GS2;
    unsigned start = Gb[bk + 1], end = Gb[bk];
    if (end > SELCAP) end = SELCAP;
    unsigned rank = 0;
    for (unsigned j = start + (unsigned)l; j < end; j += 4)
        rank += (sb[j] > my) ? 1u : 0u;

    float v = __uint_as_float(bits);
    unsigned idx = ~((unsigned)my);
    int y = (int)(idx >> 10), x = (int)(idx & 1023);
    const float* smb = s + (size_t)b * (H * W);
    float wsum = 0.f, ox = 0.f, oy = 0.f;
    for (int c = l; c < 25; c += 4) {
        int dy = c / 5 - 2, dx = c - (c / 5) * 5 - 2;
        int yy = y + dy, xx = x + dx;
        bool inb = (yy >= 0 && yy < H && xx >= 0 && xx < W);
        int yc = min(max(yy, 0), H - 1), xc = min(max(xx, 0), W - 1);
        float p = smb[yc * W + xc];
        float lg = inb ? p * 10.0f : -1e9f;   // 1/TEMPERATURE = 10
        float e = expf(lg);
        wsum += e; ox += e * (float)dx; oy += e * (float)dy;
    }
    rank += __shfl_xor(rank, 1); rank += __shfl_xor(rank, 2);
    wsum += __shfl_xor(wsum, 1); wsum += __shfl_xor(wsum, 2);
    ox   += __shfl_xor(ox, 1);   ox   += __shfl_xor(ox, 2);
    oy   += __shfl_xor(oy, 1);   oy   += __shfl_xor(oy, 2);

    unsigned frank = start + rank;
    if (l == 0 && frank < TOPK) {
        float offx = ox / wsum, offy = oy / wsum;
        out[((size_t)b * TOPK + frank) * 2 + 0] = (float)x + offx;
        out[((size_t)b * TOPK + frank) * 2 + 1] = (float)y + offy;
        out[(size_t)B * TOPK * 2 + (size_t)b * TOPK + frank] = v;
    }
}

// ---------------------------------------------------------------------------
extern "C" void kernel_launch(void* const* d_in, const int* in_sizes, int n_in,
                              void* d_out, int out_size, void* d_ws, size_t ws_size,
                              hipStream_t stream)
{
    const float* s = (const float*)d_in[0];
    float* out = (float*)d_out;
    char* ws = (char*)d_ws;

    size_t off = 0;
    unsigned* counts        = (unsigned*)(ws + off);  off += 2048;   // B*CSTRIDE*4
    unsigned* selC          = (unsigned*)(ws + off);  off += 64;
    unsigned* G             = (unsigned*)(ws + off);  off += (size_t)B * GS2 * 4;  // 630 KB
    unsigned long long* sel = (unsigned long long*)(ws + off); off += (size_t)B * SELCAP * 8; // 1 MB
    unsigned long long* cand= (unsigned long long*)(ws + off);                     // 8.4 MB

    hipMemsetAsync(counts, 0, 2048, stream);

    nms_wave<<<dim3(XSTRIPS * YSTRIPS * B / 4), dim3(256), 0, stream>>>(s, counts, cand);
    scan_scatter<<<dim3(B), dim3(1024), 0, stream>>>(counts, cand, G, selC, sel);
    rank_refine<<<dim3(SELCAP * 4 / 256, B), dim3(256), 0, stream>>>(s, sel, selC, G, out);
}

// Round 24
// 85.936 us; speedup vs baseline: 1.6277x; 1.0054x over previous
//
#include <hip/hip_runtime.h>
#include <math.h>

// Problem constants
#define B 16
#define H 1024
#define W 1024
#define TOPK 5000
#define SCORES_TH 0.2f

// selection pipeline constants
#define CAP 65536          // compact candidate cap per batch (expected ~42k)
#define SELCAP 8192        // max selected per batch
#define NB2 9831           // buckets over value bits[31:11]
#define OFFB2 510361       // bits(0.2f) >> 11
#define GS2 9840           // padded per-batch stride for G (>= NB2+1)
#define SCHUNK 10          // ceil(NB2/1024)
#define CSTRIDE 32         // counts padded 128 B apart

// wave-NMS geometry (float4 lanes — 4 cols/lane, 1 shfl/col)
#define XSTRIPS 5          // ceil(1024/252)
#define YSTRIPS 64
#define SROWS 16           // output rows per wave
#define SCOLS 252          // output cols per wave (64 lanes x 4 - 4 halo)
#define WCAP 224           // per-wave LDS key buffer (mean ~158/strip, +5 sigma)

// ---------------------------------------------------------------------------
// K0: zero the 2 KB counts region ourselves. hipMemsetAsync's
// fillBufferAligned measured 38-40 us for 2 KB inside the graph (R16 ord140,
// R23 ords 234/243/246) — a plain kernel dispatch is ~8 us.
// ---------------------------------------------------------------------------
__global__ __launch_bounds__(512) void zero_counts(unsigned* __restrict__ counts)
{
    counts[threadIdx.x] = 0u;      // 512 uints = 2048 B
}

// ---------------------------------------------------------------------------
// K1: wave-synchronous single 5x5 NMS (== double NMS, proven identity).
// FROZEN (R23): ballot-compaction emit — no LDS atomics in the hot loop;
// one global atomic per wave at flush.
// Keys: (value_bits << 32) | ~idx  (desc value, asc index) — unique per pixel.
// ---------------------------------------------------------------------------
__global__ __launch_bounds__(256) void nms_wave(
    const float* __restrict__ s,
    unsigned* __restrict__ counts,
    unsigned long long* __restrict__ cand)
{
    __shared__ unsigned long long wbuf[4][WCAP];   // 7 KB, wave-private slices
    const int tid  = threadIdx.x;
    const int w    = tid >> 6;                     // wave within block
    const int lane = tid & 63;
    const int gw   = blockIdx.x * 4 + w;           // 0 .. 5119
    const int xs   = gw % XSTRIPS;
    const int t    = gw / XSTRIPS;                 // 0 .. 1023
    const int ys   = t & (YSTRIPS - 1);
    const int b    = t >> 6;

    const float* sb = s + (size_t)b * (H * W);
    const int c0 = xs * SCOLS - 2 + 4 * lane;      // lane's first col (dword-aligned)
    const int y0 = ys * SROWS;
    const bool wfast = (xs > 0) & (xs < XSTRIPS - 1);   // wave-uniform fast path
    const unsigned long long lmlt = (lane == 63) ? ~0ull >> 1
                                                 : (1ull << lane) - 1ull; // lanes < me

    bool inb[4], emitok[4];
    #pragma unroll
    for (int j = 0; j < 4; ++j) {
        int col = c0 + j, idx4 = 4 * lane + j;
        inb[j]    = (col >= 0) & (col < W);
        emitok[j] = inb[j] & (idx4 >= 2) & (idx4 <= 253);
    }

    float ring[4][4], p1[4], p2[4];
    #pragma unroll
    for (int j = 0; j < 4; ++j) {
        ring[j][0] = ring[j][1] = ring[j][2] = ring[j][3] = -INFINITY;
        p1[j] = p2[j] = -INFINITY;
    }

    unsigned wbase = 0;                            // wave-uniform running count

    #pragma unroll 4
    for (int gy = y0 - 2; gy <= y0 + SROWS + 1; ++gy) {
        // ---- load row ------------------------------------------------------
        float a[4];
        const bool yin = (gy >= 0) & (gy < H);
        if (yin & wfast) {
            float4 v = *(const float4*)(sb + (size_t)gy * W + c0);
            a[0] = v.x; a[1] = v.y; a[2] = v.z; a[3] = v.w;
        } else if (yin) {
            #pragma unroll
            for (int j = 0; j < 4; ++j)
                a[j] = inb[j] ? sb[(size_t)gy * W + c0 + j] : -INFINITY;
        } else {
            #pragma unroll
            for (int j = 0; j < 4; ++j) a[j] = -INFINITY;
        }

        // ---- horizontal 5-max: 3 pair-maxes + 4 shfls for 4 cols -----------
        float pm01 = fmaxf(a[0], a[1]);
        float pm12 = fmaxf(a[1], a[2]);
        float pm23 = fmaxf(a[2], a[3]);
        float Lh  = __shfl_up(pm23, 1);            // cols c0-2,c0-1
        float La3 = __shfl_up(a[3], 1);            // col  c0-1
        float Ra0 = __shfl_down(a[0], 1);          // col  c0+4
        float Rp  = __shfl_down(pm01, 1);          // cols c0+4,c0+5
        float h[4];
        h[0] = fmaxf(fmaxf(Lh,  pm01), a[2]);      // c0-2..c0+2
        h[1] = fmaxf(fmaxf(La3, pm01), pm23);      // c0-1..c0+3
        h[2] = fmaxf(fmaxf(pm01, pm23), Ra0);      // c0  ..c0+4
        h[3] = fmaxf(fmaxf(pm12, pm23), Rp);       // c0+1..c0+5

        // ---- emit output row r = gy-2 via ballot compaction -----------------
        if (gy >= y0 + 2) {
            const int r = gy - 2;
            #pragma unroll
            for (int j = 0; j < 4; ++j) {
                float vm = fmaxf(fmaxf(fmaxf(ring[j][0], ring[j][1]),
                                       fmaxf(ring[j][2], ring[j][3])), h[j]);
                bool pk = emitok[j] & (p2[j] > SCORES_TH) & (p2[j] == vm);
                unsigned long long mask = __ballot(pk);
                if (pk) {
                    unsigned pi = wbase + (unsigned)__popcll(mask & lmlt);
                    unsigned idx = (unsigned)(r * W + c0 + j);
                    unsigned long long key =
                        ((unsigned long long)__float_as_uint(p2[j]) << 32) | (unsigned)(~idx);
                    if (pi < WCAP) wbuf[w][pi] = key;
                    else {                          // overflow: direct reserved write
                        unsigned gp = atomicAdd(&counts[b * CSTRIDE], 1u);
                        if (gp < CAP) cand[(size_t)b * CAP + gp] = key;
                    }
                }
                wbase += (unsigned)__popcll(mask); // wave-uniform
            }
        }

        // ---- shift rings (renamed by unroll) --------------------------------
        #pragma unroll
        for (int j = 0; j < 4; ++j) {
            ring[j][0] = ring[j][1]; ring[j][1] = ring[j][2];
            ring[j][2] = ring[j][3]; ring[j][3] = h[j];
            p2[j] = p1[j]; p1[j] = a[j];
        }
    }

    // ---- flush: one global atomic per wave, coalesced copy ------------------
    unsigned n = wbase; if (n > WCAP) n = WCAP;
    unsigned base = 0;
    if (lane == 0) base = atomicAdd(&counts[b * CSTRIDE], n);
    base = __shfl(base, 0);
    for (unsigned k = (unsigned)lane; k < n; k += 64)
        if (base + k < CAP) cand[(size_t)b * CAP + base + k] = wbuf[w][k];
}

// ---------------------------------------------------------------------------
// K2: fused LDS-histogram + wave-shfl suffix-sum scan + threshold + publish G
// + scatter (LDS cursors). One block/batch, compact cand iteration.
// FROZEN (R23). I[bk] = #{keys >= bucket bk}; segment = [I[bk+1], I[bk]).
// ---------------------------------------------------------------------------
__global__ __launch_bounds__(1024) void scan_scatter(
    const unsigned* __restrict__ counts,
    const unsigned long long* __restrict__ cand,
    unsigned* __restrict__ G,
    unsigned* __restrict__ selC,
    unsigned long long* __restrict__ sel)
{
    const int b = blockIdx.x;
    __shared__ unsigned I[NB2 + 1];   // 39.3 KB
    __shared__ unsigned wsum[16];
    __shared__ int Tsh;
    const int tid  = threadIdx.x;
    const int wv   = tid >> 6;
    const int lane = tid & 63;

    for (int i = tid; i < NB2 + 1; i += 1024) I[i] = 0;
    if (tid == 0) Tsh = 0;
    __syncthreads();

    unsigned M = counts[b * CSTRIDE]; if (M > CAP) M = CAP;
    const unsigned long long* cb = cand + (size_t)b * CAP;

    // ---- histogram over compact keys --------------------------------------
    for (unsigned i = (unsigned)tid; i < M; i += 1024) {
        unsigned bits = (unsigned)(cb[i] >> 32);
        int bk = (int)(bits >> 11) - OFFB2;
        bk = bk < 0 ? 0 : (bk > NB2 - 1 ? NB2 - 1 : bk);
        atomicAdd(&I[bk], 1u);
    }
    __syncthreads();

    // ---- suffix-sum via wave-shfl scan (2 barriers) -----------------------
    unsigned local = 0;
    #pragma unroll
    for (int u = 0; u < SCHUNK; ++u) {
        int r = tid * SCHUNK + u;
        if (r < NB2) local += I[NB2 - 1 - r];
    }
    unsigned incl = local;
    #pragma unroll
    for (int off = 1; off < 64; off <<= 1) {
        unsigned v = __shfl_up(incl, off);
        if (lane >= off) incl += v;
    }
    if (lane == 63) wsum[wv] = incl;
    __syncthreads();
    if (tid < 16) {
        unsigned o = wsum[tid];
        unsigned x = o;
        #pragma unroll
        for (int off = 1; off < 16; off <<= 1) {
            unsigned v = __shfl_up(x, off);
            if (tid >= off) x += v;
        }
        wsum[tid] = x - o;                 // exclusive prefix of wave totals
    }
    __syncthreads();
    unsigned run = wsum[wv] + (incl - local);   // thread's global exclusive prefix
    #pragma unroll
    for (int u = 0; u < SCHUNK; ++u) {
        int r = tid * SCHUNK + u;
        if (r < NB2) {
            int bk = NB2 - 1 - r;
            run += I[bk];
            I[bk] = run;                   // I becomes inclusive suffix sum
        }
    }
    __syncthreads();

    // ---- T = max bk with I[bk] >= TOPK (0 if total < TOPK) ----------------
    int localT = -1;
    #pragma unroll
    for (int u = 0; u < SCHUNK; ++u) {
        int r = tid * SCHUNK + u;
        if (r < NB2) {
            int bk = NB2 - 1 - r;
            if (I[bk] >= TOPK && bk > localT) localT = bk;
        }
    }
    if (localT >= 0) atomicMax(&Tsh, localT);
    __syncthreads();
    const int T = Tsh;
    if (tid == 0) selC[b] = I[T];

    // ---- publish clean segment table G, then scatter with LDS cursors -----
    unsigned* Gb = G + (size_t)b * GS2;
    for (int i = tid; i < NB2 + 1; i += 1024) Gb[i] = I[i];
    __syncthreads();

    for (unsigned i = (unsigned)tid; i < M; i += 1024) {
        unsigned long long key = cb[i];
        unsigned bits = (unsigned)(key >> 32);
        int bk = (int)(bits >> 11) - OFFB2;
        bk = bk < 0 ? 0 : (bk > NB2 - 1 ? NB2 - 1 : bk);
        if (bk >= T) {
            unsigned p = atomicAdd(&I[bk + 1], 1u);   // LDS cursor
            if (p < SELCAP) sel[(size_t)b * SELCAP + p] = key;
        }
    }
}

// ---------------------------------------------------------------------------
// K3: two-level exact rank, 4 lanes/key + zero-fill of ranks [C, TOPK).
// FROZEN (round 13/16).
// ---------------------------------------------------------------------------
__global__ __launch_bounds__(256) void rank_refine(
    const float* __restrict__ s,
    const unsigned long long* __restrict__ sel,
    const unsigned* __restrict__ selC,
    const unsigned* __restrict__ G,
    float* __restrict__ out)
{
    const int b = blockIdx.y;
    unsigned C = selC[b]; if (C > SELCAP) C = SELCAP;
    const int tid = threadIdx.x;
    const unsigned g = blockIdx.x * 64u + (unsigned)(tid >> 2);
    const int l = tid & 3;

    if (g >= C) {                     // zero-fill unclaimed output ranks
        if (g < TOPK && l == 0) {
            out[((size_t)b * TOPK + g) * 2 + 0] = 0.0f;
            out[((size_t)b * TOPK + g) * 2 + 1] = 0.0f;
            out[(size_t)B * TOPK * 2 + (size_t)b * TOPK + g] = 0.0f;
        }
        return;
    }

    const unsigned long long* sb = sel + (size_t)b * SELCAP;
    const unsigned long long my = sb[g];
    unsigned bits = (unsigned)(my >> 32);
    int bk = (int)(bits >> 11) - OFFB2;
    bk = bk < 0 ? 0 : (bk > NB2 - 1 ? NB2 - 1 : bk);

    const unsigned* Gb = G + (size_t)b * GS2;
    unsigned start = Gb[bk + 1], end = Gb[bk];
    if (end > SELCAP) end = SELCAP;
    unsigned rank = 0;
    for (unsigned j = start + (unsigned)l; j < end; j += 4)
        rank += (sb[j] > my) ? 1u : 0u;

    float v = __uint_as_float(bits);
    unsigned idx = ~((unsigned)my);
    int y = (int)(idx >> 10), x = (int)(idx & 1023);
    const float* smb = s + (size_t)b * (H * W);
    float wsum = 0.f, ox = 0.f, oy = 0.f;
    for (int c = l; c < 25; c += 4) {
        int dy = c / 5 - 2, dx = c - (c / 5) * 5 - 2;
        int yy = y + dy, xx = x + dx;
        bool inb = (yy >= 0 && yy < H && xx >= 0 && xx < W);
        int yc = min(max(yy, 0), H - 1), xc = min(max(xx, 0), W - 1);
        float p = smb[yc * W + xc];
        float lg = inb ? p * 10.0f : -1e9f;   // 1/TEMPERATURE = 10
        float e = expf(lg);
        wsum += e; ox += e * (float)dx; oy += e * (float)dy;
    }
    rank += __shfl_xor(rank, 1); rank += __shfl_xor(rank, 2);
    wsum += __shfl_xor(wsum, 1); wsum += __shfl_xor(wsum, 2);
    ox   += __shfl_xor(ox, 1);   ox   += __shfl_xor(ox, 2);
    oy   += __shfl_xor(oy, 1);   oy   += __shfl_xor(oy, 2);

    unsigned frank = start + rank;
    if (l == 0 && frank < TOPK) {
        float offx = ox / wsum, offy = oy / wsum;
        out[((size_t)b * TOPK + frank) * 2 + 0] = (float)x + offx;
        out[((size_t)b * TOPK + frank) * 2 + 1] = (float)y + offy;
        out[(size_t)B * TOPK * 2 + (size_t)b * TOPK + frank] = v;
    }
}

// ---------------------------------------------------------------------------
extern "C" void kernel_launch(void* const* d_in, const int* in_sizes, int n_in,
                              void* d_out, int out_size, void* d_ws, size_t ws_size,
                              hipStream_t stream)
{
    const float* s = (const float*)d_in[0];
    float* out = (float*)d_out;
    char* ws = (char*)d_ws;

    size_t off = 0;
    unsigned* counts        = (unsigned*)(ws + off);  off += 2048;   // B*CSTRIDE*4
    unsigned* selC          = (unsigned*)(ws + off);  off += 64;
    unsigned* G             = (unsigned*)(ws + off);  off += (size_t)B * GS2 * 4;  // 630 KB
    unsigned long long* sel = (unsigned long long*)(ws + off); off += (size_t)B * SELCAP * 8; // 1 MB
    unsigned long long* cand= (unsigned long long*)(ws + off);                     // 8.4 MB

    zero_counts<<<dim3(1), dim3(512), 0, stream>>>(counts);
    nms_wave<<<dim3(XSTRIPS * YSTRIPS * B / 4), dim3(256), 0, stream>>>(s, counts, cand);
    scan_scatter<<<dim3(B), dim3(1024), 0, stream>>>(counts, cand, G, selC, sel);
    rank_refine<<<dim3(SELCAP * 4 / 256, B), dim3(256), 0, stream>>>(s, sel, selC, G, out);
}